// Round 6
// baseline (509.877 us; speedup 1.0000x reference)
//
#include <hip/hip_runtime.h>
#include <math.h>

#define TPB 256
#define RB 128  // blocks per dst-range in CSR build (grid = 8*RB)

typedef short bf16x8 __attribute__((ext_vector_type(8)));
typedef float f32x4 __attribute__((ext_vector_type(4)));

static __device__ __forceinline__ float lrelu(float x) { return x > 0.f ? x : 0.2f * x; }
// fp32 -> bf16 round-to-nearest-even
static __device__ __forceinline__ unsigned short f2bf(float f) {
  unsigned u = __float_as_uint(f);
  u += 0x7fffu + ((u >> 16) & 1u);
  return (unsigned short)(u >> 16);
}
static __device__ __forceinline__ float bflo(unsigned w) { return __uint_as_float(w << 16); }
static __device__ __forceinline__ float bfhi(unsigned w) { return __uint_as_float(w & 0xffff0000u); }

// ---------------- CSR build, dst-range partitioned (XCD-local writes) ---------
// range r = blockIdx%8 -> lands on XCD r (round-robin heuristic); each range
// team sweeps the full edge list but only touches dst in [r*N/8,(r+1)*N/8) so
// its deg/cursor/csr region stays in ONE XCD's L2 (no cross-XCD line bounce).
__global__ void k_hist8(const int* __restrict__ dstE, int E, int N, int* __restrict__ deg) {
  int r = blockIdx.x & 7;
  int nb = gridDim.x >> 3;
  int lo = (int)(((long)r * N) / 8), hi = (int)(((long)(r + 1) * N) / 8);
  int EN = E + N;
  for (int e = (blockIdx.x >> 3) * TPB + threadIdx.x; e < EN; e += nb * TPB) {
    int d = (e < E) ? dstE[e] : (e - E);
    d = min(max(d, 0), N - 1);
    if (d >= lo && d < hi) atomicAdd(&deg[d], 1);
  }
}

__global__ void k_scan1(const int* __restrict__ deg, int N, int* __restrict__ csum) {
  __shared__ int sm[TPB];
  int t = threadIdx.x, i = blockIdx.x * TPB + t;
  sm[t] = (i < N) ? deg[i] : 0;
  __syncthreads();
  for (int off = TPB / 2; off; off >>= 1) {
    if (t < off) sm[t] += sm[t + off];
    __syncthreads();
  }
  if (t == 0) csum[blockIdx.x] = sm[0];
}

__global__ void k_scan2(int* __restrict__ csum, int nch) {
  __shared__ int sm[TPB];
  int t = threadIdx.x;
  int v = (t < nch) ? csum[t] : 0;
  sm[t] = v;
  __syncthreads();
  for (int off = 1; off < TPB; off <<= 1) {
    int add = (t >= off) ? sm[t - off] : 0;
    __syncthreads();
    sm[t] += add;
    __syncthreads();
  }
  if (t < nch) csum[t] = (t == 0) ? 0 : sm[t - 1];  // exclusive chunk offsets
}

__global__ void k_scan3(const int* __restrict__ deg, const int* __restrict__ csum, int N, int total,
                        int* __restrict__ row_ptr, int* __restrict__ cursor) {
  __shared__ int sm[TPB];
  int b = blockIdx.x, t = threadIdx.x, i = b * TPB + t;
  int v = (i < N) ? deg[i] : 0;
  sm[t] = v;
  __syncthreads();
  for (int off = 1; off < TPB; off <<= 1) {
    int add = (t >= off) ? sm[t - off] : 0;
    __syncthreads();
    sm[t] += add;
    __syncthreads();
  }
  if (i < N) {
    int rp = csum[b] + sm[t] - v;  // exclusive
    row_ptr[i] = rp;
    cursor[i] = rp;
  }
  if (i == 0) row_ptr[N] = total;
}

__global__ void k_scatter8(const int* __restrict__ srcE, const int* __restrict__ dstE, int E, int N,
                           int* __restrict__ cursor, int* __restrict__ csr_src) {
  int r = blockIdx.x & 7;
  int nb = gridDim.x >> 3;
  int lo = (int)(((long)r * N) / 8), hi = (int)(((long)(r + 1) * N) / 8);
  int EN = E + N;
  for (int e = (blockIdx.x >> 3) * TPB + threadIdx.x; e < EN; e += nb * TPB) {
    int d = (e < E) ? dstE[e] : (e - E);
    d = min(max(d, 0), N - 1);
    if (d >= lo && d < hi) {
      int s = (e < E) ? srcE[e] : (e - E);
      s = min(max(s, 0), N - 1);
      int pos = atomicAdd(&cursor[d], 1);
      csr_src[pos] = s;
    }
  }
}

// ---------------- fp32 -> bf16 convert (8 elems/thread) -----------------------
__global__ void k_f2b(const float4* __restrict__ in, uint4* __restrict__ out, int n8) {
  int i = blockIdx.x * TPB + threadIdx.x;
  if (i >= n8) return;
  float4 v0 = in[i * 2], v1 = in[i * 2 + 1];
  uint4 o;
  o.x = (unsigned)f2bf(v0.x) | ((unsigned)f2bf(v0.y) << 16);
  o.y = (unsigned)f2bf(v0.z) | ((unsigned)f2bf(v0.w) << 16);
  o.z = (unsigned)f2bf(v1.x) | ((unsigned)f2bf(v1.y) << 16);
  o.w = (unsigned)f2bf(v1.z) | ((unsigned)f2bf(v1.w) << 16);
  out[i] = o;
}

// Wb[col][k] bf16 for BOTH layers in one launch (grid 512, block 128)
__global__ void k_prep_w2(const float* __restrict__ cW0, const float* __restrict__ sW0,
                          const float* __restrict__ cW1, const float* __restrict__ sW1,
                          unsigned short* __restrict__ Wb0, unsigned short* __restrict__ Wb1) {
  int j = blockIdx.x & 255;
  int which = blockIdx.x >> 8;
  int k = threadIdx.x;
  const float* cW = which ? cW1 : cW0;
  const float* sW = which ? sW1 : sW0;
  unsigned short* Wb = which ? Wb1 : Wb0;
  Wb[j * 128 + k] = f2bf((j < 128) ? cW[k * 128 + j] : sW[(j - 128) * 128 + k]);
}

// ---------------- MFMA GEMM: [H16 | Sk16] = Xb @ Wb^T (bf16 in, fp32 acc) -----
__global__ __launch_bounds__(TPB) void k_gemm_mfma(const unsigned short* __restrict__ Xb,
                                                   const unsigned short* __restrict__ Wb,
                                                   unsigned short* __restrict__ H16,
                                                   unsigned short* __restrict__ Sk16, int NR) {
  int wid = threadIdx.x >> 6, lane = threadIdx.x & 63;
  int r0 = blockIdx.x * 64;
  int c0 = wid * 64;
  int l15 = lane & 15, lk = lane >> 4;

  f32x4 acc[4][4];
#pragma unroll
  for (int i = 0; i < 4; ++i)
#pragma unroll
    for (int j = 0; j < 4; ++j) acc[i][j] = (f32x4){0.f, 0.f, 0.f, 0.f};

#pragma unroll
  for (int ks = 0; ks < 4; ++ks) {
    bf16x8 a[4], b[4];
#pragma unroll
    for (int rt = 0; rt < 4; ++rt) {
      int row = min(r0 + rt * 16 + l15, NR - 1);
      a[rt] = *(const bf16x8*)(Xb + (size_t)row * 128 + ks * 32 + lk * 8);
    }
#pragma unroll
    for (int ct = 0; ct < 4; ++ct) {
      int col = c0 + ct * 16 + l15;
      b[ct] = *(const bf16x8*)(Wb + (size_t)col * 128 + ks * 32 + lk * 8);
    }
#pragma unroll
    for (int rt = 0; rt < 4; ++rt)
#pragma unroll
      for (int ct = 0; ct < 4; ++ct)
        acc[rt][ct] = __builtin_amdgcn_mfma_f32_16x16x32_bf16(a[rt], b[ct], acc[rt][ct], 0, 0, 0);
  }

  int orow = lk * 4;  // D: col = lane&15, row = (lane>>4)*4 + reg
#pragma unroll
  for (int rt = 0; rt < 4; ++rt) {
#pragma unroll
    for (int ct = 0; ct < 4; ++ct) {
      int col = c0 + ct * 16 + l15;
#pragma unroll
      for (int r = 0; r < 4; ++r) {
        int row = r0 + rt * 16 + orow + r;
        if (row < NR) {
          float v = acc[rt][ct][r];
          if (col < 128)
            H16[(size_t)row * 128 + col] = f2bf(v);
          else
            Sk16[(size_t)row * 128 + (col - 128)] = f2bf(v);
        }
      }
    }
  }
}

// ---------------- per-node attention coefficients a_s, a_d (bf16 H) ----------
__global__ void k_asad(const unsigned short* __restrict__ H16, const float* __restrict__ asrc,
                       const float* __restrict__ adst, float* __restrict__ a_s, float* __restrict__ a_d, int N) {
  int i = blockIdx.x * TPB + threadIdx.x;
  if (i >= N * 4) return;
  int n = i >> 2, h = i & 3;
  const uint4* hp = (const uint4*)(H16 + (size_t)n * 128 + h * 32);
  const float4* ap = (const float4*)(asrc + h * 32);
  const float4* bp = (const float4*)(adst + h * 32);
  float sa = 0.f, sd = 0.f;
#pragma unroll
  for (int q = 0; q < 4; ++q) {
    uint4 v = hp[q];
    float f0 = bflo(v.x), f1 = bfhi(v.x), f2 = bflo(v.y), f3 = bfhi(v.y);
    float f4 = bflo(v.z), f5 = bfhi(v.z), f6 = bflo(v.w), f7 = bfhi(v.w);
    float4 a0 = ap[q * 2], a1 = ap[q * 2 + 1];
    float4 b0 = bp[q * 2], b1 = bp[q * 2 + 1];
    sa += f0 * a0.x + f1 * a0.y + f2 * a0.z + f3 * a0.w + f4 * a1.x + f5 * a1.y + f6 * a1.z + f7 * a1.w;
    sd += f0 * b0.x + f1 * b0.y + f2 * b0.z + f3 * b0.w + f4 * b1.x + f5 * b1.y + f6 * b1.z + f7 * b1.w;
  }
  a_s[i] = sa;
  a_d[i] = sd;
}

// ---------------- fused softmax + aggregate, channel-sliced -------------------
// wave = (node n, 32-ch slice s). slice s -> XCD pair {2s,2s+1} via blockIdx%8,
// so each XCD's H16 gather working set is N*64B = 3.2 MB (L2-resident).
// A 32-ch slice == one head -> scalar softmax. Aggregation: 4 edge-groups x
// 16 channel-lanes; each edge gather = one 64B line.
template <bool BF>
__global__ __launch_bounds__(TPB) void k_smax_agg(const int* __restrict__ row_ptr, const int* __restrict__ csr_src,
                                                  const float* __restrict__ a_s, const float* __restrict__ a_d,
                                                  const unsigned short* __restrict__ H16,
                                                  const unsigned short* __restrict__ Sk16,
                                                  const float* __restrict__ cb, const float* __restrict__ sb,
                                                  float* __restrict__ spill, float* __restrict__ XnF,
                                                  unsigned short* __restrict__ XnB, int N) {
  __shared__ int s_src[4][64];
  __shared__ float s_al[4][64];
  int b = blockIdx.x;
  int s = (b & 7) >> 1;            // slice/head 0..3, pinned to XCD pair
  int q = ((b >> 3) << 1) + (b & 1);  // node-quad index
  int wid = threadIdx.x >> 6;
  int n = q * 4 + wid;
  if (n >= N) return;
  int lane = threadIdx.x & 63;
  int eg = lane >> 4, cl = lane & 15;
  int c = s * 32 + cl * 2;  // channel pair owned by this lane (within groups)
  int beg = row_ptr[n], end = row_ptr[n + 1];
  int deg = end - beg;
  float ad = a_d[n * 4 + s];
  float acc0 = 0.f, acc1 = 0.f;

  if (deg <= 64) {
    int s_l = 0;
    float lg = -1e30f;
    if (lane < deg) {
      s_l = csr_src[beg + lane];
      lg = lrelu(a_s[s_l * 4 + s] + ad);
    }
    int maxoff = (deg <= 16) ? 8 : (deg <= 32) ? 16 : 32;  // wave-uniform
    float mx = lg;
    for (int off = 1; off <= maxoff; off <<= 1) mx = fmaxf(mx, __shfl_xor(mx, off));
    float pv = (lane < deg) ? __expf(lg - mx) : 0.f;
    float sm = pv;
    for (int off = 1; off <= maxoff; off <<= 1) sm += __shfl_xor(sm, off);
    pv *= 1.f / (sm + 1e-16f);
    s_src[wid][lane] = s_l;
    s_al[wid][lane] = pv;
    __builtin_amdgcn_wave_barrier();  // wave-synchronous LDS ordering

    const unsigned short* Hb = H16 + c;
    int dpad = (deg + 3) & ~3;
    for (int j = 0; j < dpad; j += 4) {
      int sj = s_src[wid][j + eg];
      float aj = s_al[wid][j + eg];
      unsigned w = *(const unsigned*)(Hb + (size_t)sj * 128);
      acc0 = fmaf(aj, bflo(w), acc0);
      acc1 = fmaf(aj, bfhi(w), acc1);
    }
  } else {
    // slow path (deg>64, ~never): spill scalar logits to global
    float mx = -1e30f;
    for (int p = beg + lane; p < end; p += 64) {
      float lg = lrelu(a_s[csr_src[p] * 4 + s] + ad);
      spill[(size_t)p * 4 + s] = lg;
      mx = fmaxf(mx, lg);
    }
#pragma unroll
    for (int off = 32; off; off >>= 1) mx = fmaxf(mx, __shfl_xor(mx, off));
    __threadfence_block();
    float sm = 0.f;
    for (int p = beg + lane; p < end; p += 64) {
      float pv = __expf(spill[(size_t)p * 4 + s] - mx);
      spill[(size_t)p * 4 + s] = pv;
      sm += pv;
    }
#pragma unroll
    for (int off = 32; off; off >>= 1) sm += __shfl_xor(sm, off);
    float inv = 1.f / (sm + 1e-16f);
    __threadfence_block();
    for (int j = 0; j < deg; j += 4) {
      int p = beg + j + eg;
      if (p < end) {
        int sj = csr_src[p];
        float aj = spill[(size_t)p * 4 + s] * inv;
        unsigned w = *(const unsigned*)(H16 + (size_t)sj * 128 + c);
        acc0 = fmaf(aj, bflo(w), acc0);
        acc1 = fmaf(aj, bfhi(w), acc1);
      }
    }
  }

  // reduce across the 4 edge-groups
  acc0 += __shfl_xor(acc0, 16);
  acc0 += __shfl_xor(acc0, 32);
  acc1 += __shfl_xor(acc1, 16);
  acc1 += __shfl_xor(acc1, 32);

  if (eg == 0) {
    unsigned skw = *(const unsigned*)(Sk16 + (size_t)n * 128 + c);
    float2 cbv = *(const float2*)(cb + c);
    float2 sbv = *(const float2*)(sb + c);
    float ox = fmaxf(acc0 + cbv.x + bflo(skw) + sbv.x, 0.f);
    float oy = fmaxf(acc1 + cbv.y + bfhi(skw) + sbv.y, 0.f);
    if (BF) {
      unsigned pk = (unsigned)f2bf(ox) | ((unsigned)f2bf(oy) << 16);
      *(unsigned*)(XnB + (size_t)n * 128 + c) = pk;
    } else {
      *(float2*)(XnF + (size_t)n * 128 + c) = make_float2(ox, oy);
    }
  }
}

// ---------------- layer 2 (H=1, C=1) -----------------------------------------
__global__ void k_l2_lin(const float* __restrict__ X, const float* __restrict__ c2w, const float* __restrict__ s2w,
                         const float* __restrict__ c2as, const float* __restrict__ c2ad, float* __restrict__ h2,
                         float* __restrict__ sk2, float* __restrict__ as2, float* __restrict__ ad2, int N) {
  int gid = blockIdx.x * TPB + threadIdx.x;
  int n = gid >> 6;
  int lane = threadIdx.x & 63;
  if (n >= N) return;
  const float* xp = X + (size_t)n * 128;
  float2 xv = *(const float2*)(xp + lane * 2);
  float2 wv = *(const float2*)(c2w + lane * 2);
  float2 sv = *(const float2*)(s2w + lane * 2);
  float dh = xv.x * wv.x + xv.y * wv.y;
  float ds = xv.x * sv.x + xv.y * sv.y;
  for (int off = 32; off; off >>= 1) {
    dh += __shfl_down(dh, off);
    ds += __shfl_down(ds, off);
  }
  if (lane == 0) {
    h2[n] = dh;
    sk2[n] = ds;
    as2[n] = dh * c2as[0];
    ad2[n] = dh * c2ad[0];
  }
}

// fused softmax + aggregate (H=1, C=1), wave-per-node
__global__ __launch_bounds__(TPB) void k_l2_smax_agg(const int* __restrict__ row_ptr, const int* __restrict__ csr_src,
                                                     const float* __restrict__ as2, const float* __restrict__ ad2,
                                                     const float* __restrict__ h2, const float* __restrict__ sk2,
                                                     const float* __restrict__ c2b, const float* __restrict__ s2b,
                                                     float* __restrict__ out, int N) {
  int n = blockIdx.x * 4 + (threadIdx.x >> 6);
  if (n >= N) return;
  int lane = threadIdx.x & 63;
  int beg = row_ptr[n], end = row_ptr[n + 1];
  int deg = end - beg;
  float ad = ad2[n];
  float num = 0.f, den = 0.f;

  if (deg <= 64) {
    float lg = -1e30f, hv = 0.f;
    if (lane < deg) {
      int s = csr_src[beg + lane];
      lg = lrelu(as2[s] + ad);
      hv = h2[s];
    }
    float mx = lg;
#pragma unroll
    for (int off = 32; off; off >>= 1) mx = fmaxf(mx, __shfl_xor(mx, off));
    float pv = (lane < deg) ? __expf(lg - mx) : 0.f;
    num = pv * hv;
    den = pv;
  } else {
    float mx = -1e30f;
    for (int p = beg + lane; p < end; p += 64) mx = fmaxf(mx, lrelu(as2[csr_src[p]] + ad));
#pragma unroll
    for (int off = 32; off; off >>= 1) mx = fmaxf(mx, __shfl_xor(mx, off));
    for (int p = beg + lane; p < end; p += 64) {
      int s = csr_src[p];
      float pv = __expf(lrelu(as2[s] + ad) - mx);
      num += pv * h2[s];
      den += pv;
    }
  }
#pragma unroll
  for (int off = 32; off; off >>= 1) {
    num += __shfl_xor(num, off);
    den += __shfl_xor(den, off);
  }
  if (lane == 0) {
    float v = num / (den + 1e-16f) + c2b[0] + sk2[n] + s2b[0];
    out[n] = 1.f / (1.f + __expf(-v));
  }
}

// ---------------- host orchestration -----------------------------------------
extern "C" void kernel_launch(void* const* d_in, const int* in_sizes, int n_in,
                              void* d_out, int out_size, void* d_ws, size_t ws_size,
                              hipStream_t stream) {
  const float* x = (const float*)d_in[0];
  const int* ei = (const int*)d_in[1];
  const float* c0_w = (const float*)d_in[3];
  const float* c0_as = (const float*)d_in[4];
  const float* c0_ad = (const float*)d_in[5];
  const float* c0_b = (const float*)d_in[6];
  const float* s0_w = (const float*)d_in[7];
  const float* s0_b = (const float*)d_in[8];
  const float* c1_w = (const float*)d_in[9];
  const float* c1_as = (const float*)d_in[10];
  const float* c1_ad = (const float*)d_in[11];
  const float* c1_b = (const float*)d_in[12];
  const float* s1_w = (const float*)d_in[13];
  const float* s1_b = (const float*)d_in[14];
  const float* c2_w = (const float*)d_in[15];
  const float* c2_as = (const float*)d_in[16];
  const float* c2_ad = (const float*)d_in[17];
  const float* c2_b = (const float*)d_in[18];
  const float* s2_w = (const float*)d_in[19];
  const float* s2_b = (const float*)d_in[20];

  const int N = in_sizes[0] / 128;
  const int E = in_sizes[1] / 2;
  const int EN = E + N;
  const int* srcE = ei;
  const int* dstE = ei + E;

  // bump allocator over d_ws
  char* wp_ = (char*)d_ws;
  auto alloc = [&](size_t bytes) -> void* {
    void* r = (void*)wp_;
    wp_ += (bytes + 255) & ~(size_t)255;
    return r;
  };
  unsigned short* Xb0 = (unsigned short*)alloc((size_t)N * 128 * 2);   // bf16 layer-0 input
  unsigned short* Xb1 = (unsigned short*)alloc((size_t)N * 128 * 2);   // bf16 layer-1 input
  unsigned short* H16 = (unsigned short*)alloc((size_t)N * 128 * 2);   // bf16 lin out
  unsigned short* Sk16 = (unsigned short*)alloc((size_t)N * 128 * 2);  // bf16 skip
  float* P2 = (float*)alloc((size_t)N * 128 * 4);                      // layer-1 out (fp32)
  float* a_s = (float*)alloc((size_t)N * 4 * 4);
  float* a_d = (float*)alloc((size_t)N * 4 * 4);
  float* spill = (float*)alloc((size_t)EN * 4 * 4);  // slow-path alpha spill
  unsigned short* Wb0 = (unsigned short*)alloc(256 * 128 * 2);
  unsigned short* Wb1 = (unsigned short*)alloc(256 * 128 * 2);
  int* deg = (int*)alloc((size_t)N * 4);
  int* row_ptr = (int*)alloc((size_t)(N + 1) * 4);
  int* cursor = (int*)alloc((size_t)N * 4);
  int* csum = (int*)alloc(4096 * 4);
  int* csr_src = (int*)alloc((size_t)EN * 4);
  float* h2 = (float*)alloc((size_t)N * 4);
  float* sk2 = (float*)alloc((size_t)N * 4);
  float* as2 = (float*)alloc((size_t)N * 4);
  float* ad2 = (float*)alloc((size_t)N * 4);

  const int gN4 = (N * 4 + TPB - 1) / TPB;
  const int nch = (N + TPB - 1) / TPB;
  const int gGemm = (N + 63) / 64;
  const int gWave = (N + 3) / 4;           // l2 kernels: 4 nodes/block
  const int gSlice = ((N + 7) / 8) * 8;    // sliced smax_agg
  const int n8 = N * 128 / 8;

  // ---- CSR build (once per call; graph shared by all layers) ----
  hipMemsetAsync(deg, 0, (size_t)N * 4, stream);
  k_hist8<<<8 * RB, TPB, 0, stream>>>(dstE, E, N, deg);
  k_scan1<<<nch, TPB, 0, stream>>>(deg, N, csum);
  k_scan2<<<1, TPB, 0, stream>>>(csum, nch);
  k_scan3<<<nch, TPB, 0, stream>>>(deg, csum, N, EN, row_ptr, cursor);
  k_scatter8<<<8 * RB, TPB, 0, stream>>>(srcE, dstE, E, N, cursor, csr_src);

  // ---- shared prep ----
  k_f2b<<<(n8 + TPB - 1) / TPB, TPB, 0, stream>>>((const float4*)x, (uint4*)Xb0, n8);
  k_prep_w2<<<512, 128, 0, stream>>>(c0_w, s0_w, c1_w, s1_w, Wb0, Wb1);

  // ---- layer 0 ----
  k_gemm_mfma<<<gGemm, TPB, 0, stream>>>(Xb0, Wb0, H16, Sk16, N);
  k_asad<<<gN4, TPB, 0, stream>>>(H16, c0_as, c0_ad, a_s, a_d, N);
  k_smax_agg<true><<<gSlice, TPB, 0, stream>>>(row_ptr, csr_src, a_s, a_d, H16, Sk16, c0_b, s0_b, spill, nullptr,
                                               Xb1, N);

  // ---- layer 1 ----
  k_gemm_mfma<<<gGemm, TPB, 0, stream>>>(Xb1, Wb1, H16, Sk16, N);
  k_asad<<<gN4, TPB, 0, stream>>>(H16, c1_as, c1_ad, a_s, a_d, N);
  k_smax_agg<false><<<gSlice, TPB, 0, stream>>>(row_ptr, csr_src, a_s, a_d, H16, Sk16, c1_b, s1_b, spill, P2,
                                                nullptr, N);

  // ---- layer 2 (H=1,C=1) ----
  k_l2_lin<<<(N * 64 + TPB - 1) / TPB, TPB, 0, stream>>>(P2, c2_w, s2_w, c2_as, c2_ad, h2, sk2, as2, ad2, N);
  k_l2_smax_agg<<<gWave, TPB, 0, stream>>>(row_ptr, csr_src, as2, ad2, h2, sk2, c2_b, s2_b, (float*)d_out, N);
}

// Round 7
// 367.612 us; speedup vs baseline: 1.3870x; 1.3870x over previous
//
#include <hip/hip_runtime.h>
#include <math.h>

#define TPB 256
#define RB 128  // blocks per dst-range in CSR build (grid = 8*RB)

typedef short bf16x8 __attribute__((ext_vector_type(8)));
typedef float f32x4 __attribute__((ext_vector_type(4)));

static __device__ __forceinline__ float lrelu(float x) { return x > 0.f ? x : 0.2f * x; }
// fp32 -> bf16 round-to-nearest-even
static __device__ __forceinline__ unsigned short f2bf(float f) {
  unsigned u = __float_as_uint(f);
  u += 0x7fffu + ((u >> 16) & 1u);
  return (unsigned short)(u >> 16);
}
static __device__ __forceinline__ float bflo(unsigned w) { return __uint_as_float(w << 16); }
static __device__ __forceinline__ float bfhi(unsigned w) { return __uint_as_float(w & 0xffff0000u); }
static __device__ __forceinline__ bf16x8 pack8(float4 v0, float4 v1) {
  bf16x8 r;
  r[0] = (short)f2bf(v0.x);
  r[1] = (short)f2bf(v0.y);
  r[2] = (short)f2bf(v0.z);
  r[3] = (short)f2bf(v0.w);
  r[4] = (short)f2bf(v1.x);
  r[5] = (short)f2bf(v1.y);
  r[6] = (short)f2bf(v1.z);
  r[7] = (short)f2bf(v1.w);
  return r;
}

// ---------------- CSR build, dst-range partitioned (XCD-local writes) ---------
__global__ void k_hist8(const int* __restrict__ dstE, int E, int N, int* __restrict__ deg) {
  int r = blockIdx.x & 7;
  int nb = gridDim.x >> 3;
  int lo = (int)(((long)r * N) / 8), hi = (int)(((long)(r + 1) * N) / 8);
  int EN = E + N;
  for (int e = (blockIdx.x >> 3) * TPB + threadIdx.x; e < EN; e += nb * TPB) {
    int d = (e < E) ? dstE[e] : (e - E);
    d = min(max(d, 0), N - 1);
    if (d >= lo && d < hi) atomicAdd(&deg[d], 1);
  }
}

__global__ void k_scan1(const int* __restrict__ deg, int N, int* __restrict__ csum) {
  __shared__ int sm[TPB];
  int t = threadIdx.x, i = blockIdx.x * TPB + t;
  sm[t] = (i < N) ? deg[i] : 0;
  __syncthreads();
  for (int off = TPB / 2; off; off >>= 1) {
    if (t < off) sm[t] += sm[t + off];
    __syncthreads();
  }
  if (t == 0) csum[blockIdx.x] = sm[0];
}

__global__ void k_scan2(int* __restrict__ csum, int nch) {
  __shared__ int sm[TPB];
  int t = threadIdx.x;
  int v = (t < nch) ? csum[t] : 0;
  sm[t] = v;
  __syncthreads();
  for (int off = 1; off < TPB; off <<= 1) {
    int add = (t >= off) ? sm[t - off] : 0;
    __syncthreads();
    sm[t] += add;
    __syncthreads();
  }
  if (t < nch) csum[t] = (t == 0) ? 0 : sm[t - 1];  // exclusive chunk offsets
}

__global__ void k_scan3(const int* __restrict__ deg, const int* __restrict__ csum, int N, int total,
                        int* __restrict__ row_ptr, int* __restrict__ cursor) {
  __shared__ int sm[TPB];
  int b = blockIdx.x, t = threadIdx.x, i = b * TPB + t;
  int v = (i < N) ? deg[i] : 0;
  sm[t] = v;
  __syncthreads();
  for (int off = 1; off < TPB; off <<= 1) {
    int add = (t >= off) ? sm[t - off] : 0;
    __syncthreads();
    sm[t] += add;
    __syncthreads();
  }
  if (i < N) {
    int rp = csum[b] + sm[t] - v;  // exclusive
    row_ptr[i] = rp;
    cursor[i] = rp;
  }
  if (i == 0) row_ptr[N] = total;
}

__global__ void k_scatter8(const int* __restrict__ srcE, const int* __restrict__ dstE, int E, int N,
                           int* __restrict__ cursor, int* __restrict__ csr_src) {
  int r = blockIdx.x & 7;
  int nb = gridDim.x >> 3;
  int lo = (int)(((long)r * N) / 8), hi = (int)(((long)(r + 1) * N) / 8);
  int EN = E + N;
  for (int e = (blockIdx.x >> 3) * TPB + threadIdx.x; e < EN; e += nb * TPB) {
    int d = (e < E) ? dstE[e] : (e - E);
    d = min(max(d, 0), N - 1);
    if (d >= lo && d < hi) {
      int s = (e < E) ? srcE[e] : (e - E);
      s = min(max(s, 0), N - 1);
      int pos = atomicAdd(&cursor[d], 1);
      csr_src[pos] = s;
    }
  }
}

// Wb[col][k] bf16 for BOTH layers in one launch (grid 512, block 128)
__global__ void k_prep_w2(const float* __restrict__ cW0, const float* __restrict__ sW0,
                          const float* __restrict__ cW1, const float* __restrict__ sW1,
                          unsigned short* __restrict__ Wb0, unsigned short* __restrict__ Wb1) {
  int j = blockIdx.x & 255;
  int which = blockIdx.x >> 8;
  int k = threadIdx.x;
  const float* cW = which ? cW1 : cW0;
  const float* sW = which ? sW1 : sW0;
  unsigned short* Wb = which ? Wb1 : Wb0;
  Wb[j * 128 + k] = f2bf((j < 128) ? cW[k * 128 + j] : sW[(j - 128) * 128 + k]);
}

// ---------------- MFMA GEMM: [H16 | Sk16] = X @ Wb^T (bf16 in, fp32 acc) ------
// F32IN: load fp32 X and convert in-register (layer 0); else bf16 input.
template <bool F32IN>
__global__ __launch_bounds__(TPB) void k_gemm_mfma(const void* __restrict__ Xv,
                                                   const unsigned short* __restrict__ Wb,
                                                   unsigned short* __restrict__ H16,
                                                   unsigned short* __restrict__ Sk16, int NR) {
  int wid = threadIdx.x >> 6, lane = threadIdx.x & 63;
  int r0 = blockIdx.x * 64;
  int c0 = wid * 64;
  int l15 = lane & 15, lk = lane >> 4;

  f32x4 acc[4][4];
#pragma unroll
  for (int i = 0; i < 4; ++i)
#pragma unroll
    for (int j = 0; j < 4; ++j) acc[i][j] = (f32x4){0.f, 0.f, 0.f, 0.f};

#pragma unroll
  for (int ks = 0; ks < 4; ++ks) {
    bf16x8 a[4], b[4];
#pragma unroll
    for (int rt = 0; rt < 4; ++rt) {
      int row = min(r0 + rt * 16 + l15, NR - 1);
      if (F32IN) {
        const float* xp = (const float*)Xv + (size_t)row * 128 + ks * 32 + lk * 8;
        a[rt] = pack8(*(const float4*)xp, *(const float4*)(xp + 4));
      } else {
        a[rt] = *(const bf16x8*)((const unsigned short*)Xv + (size_t)row * 128 + ks * 32 + lk * 8);
      }
    }
#pragma unroll
    for (int ct = 0; ct < 4; ++ct) {
      int col = c0 + ct * 16 + l15;
      b[ct] = *(const bf16x8*)(Wb + (size_t)col * 128 + ks * 32 + lk * 8);
    }
#pragma unroll
    for (int rt = 0; rt < 4; ++rt)
#pragma unroll
      for (int ct = 0; ct < 4; ++ct)
        acc[rt][ct] = __builtin_amdgcn_mfma_f32_16x16x32_bf16(a[rt], b[ct], acc[rt][ct], 0, 0, 0);
  }

  int orow = lk * 4;  // D: col = lane&15, row = (lane>>4)*4 + reg
#pragma unroll
  for (int rt = 0; rt < 4; ++rt) {
#pragma unroll
    for (int ct = 0; ct < 4; ++ct) {
      int col = c0 + ct * 16 + l15;
#pragma unroll
      for (int r = 0; r < 4; ++r) {
        int row = r0 + rt * 16 + orow + r;
        if (row < NR) {
          float v = acc[rt][ct][r];
          if (col < 128)
            H16[(size_t)row * 128 + col] = f2bf(v);
          else
            Sk16[(size_t)row * 128 + (col - 128)] = f2bf(v);
        }
      }
    }
  }
}

// ---------------- per-node attention coefficients a_s, a_d (bf16 H) ----------
__global__ void k_asad(const unsigned short* __restrict__ H16, const float* __restrict__ asrc,
                       const float* __restrict__ adst, float* __restrict__ a_s, float* __restrict__ a_d, int N) {
  int i = blockIdx.x * TPB + threadIdx.x;
  if (i >= N * 4) return;
  int n = i >> 2, h = i & 3;
  const uint4* hp = (const uint4*)(H16 + (size_t)n * 128 + h * 32);
  const float4* ap = (const float4*)(asrc + h * 32);
  const float4* bp = (const float4*)(adst + h * 32);
  float sa = 0.f, sd = 0.f;
#pragma unroll
  for (int q = 0; q < 4; ++q) {
    uint4 v = hp[q];
    float f0 = bflo(v.x), f1 = bfhi(v.x), f2 = bflo(v.y), f3 = bfhi(v.y);
    float f4 = bflo(v.z), f5 = bfhi(v.z), f6 = bflo(v.w), f7 = bfhi(v.w);
    float4 a0 = ap[q * 2], a1 = ap[q * 2 + 1];
    float4 b0 = bp[q * 2], b1 = bp[q * 2 + 1];
    sa += f0 * a0.x + f1 * a0.y + f2 * a0.z + f3 * a0.w + f4 * a1.x + f5 * a1.y + f6 * a1.z + f7 * a1.w;
    sd += f0 * b0.x + f1 * b0.y + f2 * b0.z + f3 * b0.w + f4 * b1.x + f5 * b1.y + f6 * b1.z + f7 * b1.w;
  }
  a_s[i] = sa;
  a_d[i] = sd;
}

// ---------------- fused softmax + aggregate, wave-per-node (H=4) --------------
// BF: write bf16 Xn (feeds next MFMA GEMM). L2F: instead of storing the 128-ch
// row, fuse the layer-2 linear: wave-reduce dots with c2w/s2w -> h2/sk2/as2/ad2
// (P2 never materialized).
template <bool BF, bool L2F>
__global__ __launch_bounds__(TPB) void k_smax_agg(
    const int* __restrict__ row_ptr, const int* __restrict__ csr_src, const float4* __restrict__ a_s4,
    const float4* __restrict__ a_d4, const unsigned short* __restrict__ H16,
    const unsigned short* __restrict__ Sk16, const float* __restrict__ cb, const float* __restrict__ sb,
    float4* __restrict__ spill, unsigned short* __restrict__ XnB, const float* __restrict__ c2w,
    const float* __restrict__ s2w, const float* __restrict__ c2as, const float* __restrict__ c2ad,
    float* __restrict__ h2, float* __restrict__ sk2, float* __restrict__ as2, float* __restrict__ ad2, int N) {
  __shared__ int s_src[4][64];
  __shared__ float s_al[4][256];
  int wid = threadIdx.x >> 6;
  int n = blockIdx.x * 4 + wid;
  if (n >= N) return;
  int lane = threadIdx.x & 63;
  int beg = row_ptr[n], end = row_ptr[n + 1];
  int deg = end - beg;
  float4 ad = a_d4[n];
  int h = lane >> 4;
  float acc0 = 0.f, acc1 = 0.f;

  if (deg <= 64) {
    int s_l = 0;
    float4 lg = make_float4(-1e30f, -1e30f, -1e30f, -1e30f);
    if (lane < deg) {
      s_l = csr_src[beg + lane];
      float4 as = a_s4[s_l];
      lg.x = lrelu(as.x + ad.x);
      lg.y = lrelu(as.y + ad.y);
      lg.z = lrelu(as.z + ad.z);
      lg.w = lrelu(as.w + ad.w);
    }
    int maxoff = (deg <= 16) ? 8 : (deg <= 32) ? 16 : 32;  // wave-uniform
    float4 mx = lg;
    for (int off = 1; off <= maxoff; off <<= 1) {
      mx.x = fmaxf(mx.x, __shfl_xor(mx.x, off));
      mx.y = fmaxf(mx.y, __shfl_xor(mx.y, off));
      mx.z = fmaxf(mx.z, __shfl_xor(mx.z, off));
      mx.w = fmaxf(mx.w, __shfl_xor(mx.w, off));
    }
    float4 pv = make_float4(0.f, 0.f, 0.f, 0.f);
    if (lane < deg) {
      pv.x = __expf(lg.x - mx.x);
      pv.y = __expf(lg.y - mx.y);
      pv.z = __expf(lg.z - mx.z);
      pv.w = __expf(lg.w - mx.w);
    }
    float4 sm = pv;
    for (int off = 1; off <= maxoff; off <<= 1) {
      sm.x += __shfl_xor(sm.x, off);
      sm.y += __shfl_xor(sm.y, off);
      sm.z += __shfl_xor(sm.z, off);
      sm.w += __shfl_xor(sm.w, off);
    }
    pv.x *= 1.f / (sm.x + 1e-16f);
    pv.y *= 1.f / (sm.y + 1e-16f);
    pv.z *= 1.f / (sm.z + 1e-16f);
    pv.w *= 1.f / (sm.w + 1e-16f);
    s_src[wid][lane] = s_l;
    *(float4*)&s_al[wid][lane * 4] = pv;
    __builtin_amdgcn_wave_barrier();  // order LDS writes before reads (wave-synchronous)

    const unsigned short* Hb = H16 + lane * 2;
    int dpad = (deg + 3) & ~3;
    for (int j = 0; j < dpad; j += 4) {
      int s0 = s_src[wid][j + 0];
      int s1 = s_src[wid][j + 1];
      int s2 = s_src[wid][j + 2];
      int s3 = s_src[wid][j + 3];
      float a0 = s_al[wid][(j + 0) * 4 + h];
      float a1 = s_al[wid][(j + 1) * 4 + h];
      float a2 = s_al[wid][(j + 2) * 4 + h];
      float a3 = s_al[wid][(j + 3) * 4 + h];
      unsigned w0 = *(const unsigned*)(Hb + (size_t)s0 * 128);
      unsigned w1 = *(const unsigned*)(Hb + (size_t)s1 * 128);
      unsigned w2 = *(const unsigned*)(Hb + (size_t)s2 * 128);
      unsigned w3 = *(const unsigned*)(Hb + (size_t)s3 * 128);
      acc0 = fmaf(a0, bflo(w0), acc0);
      acc1 = fmaf(a0, bfhi(w0), acc1);
      acc0 = fmaf(a1, bflo(w1), acc0);
      acc1 = fmaf(a1, bfhi(w1), acc1);
      acc0 = fmaf(a2, bflo(w2), acc0);
      acc1 = fmaf(a2, bfhi(w2), acc1);
      acc0 = fmaf(a3, bflo(w3), acc0);
      acc1 = fmaf(a3, bfhi(w3), acc1);
    }
  } else {
    // slow path (deg>64): spill logits to global
    float4 mx = make_float4(-1e30f, -1e30f, -1e30f, -1e30f);
    for (int p = beg + lane; p < end; p += 64) {
      int s = csr_src[p];
      float4 as = a_s4[s];
      float4 lg;
      lg.x = lrelu(as.x + ad.x);
      lg.y = lrelu(as.y + ad.y);
      lg.z = lrelu(as.z + ad.z);
      lg.w = lrelu(as.w + ad.w);
      spill[p] = lg;
      mx.x = fmaxf(mx.x, lg.x);
      mx.y = fmaxf(mx.y, lg.y);
      mx.z = fmaxf(mx.z, lg.z);
      mx.w = fmaxf(mx.w, lg.w);
    }
#pragma unroll
    for (int off = 32; off; off >>= 1) {
      mx.x = fmaxf(mx.x, __shfl_xor(mx.x, off));
      mx.y = fmaxf(mx.y, __shfl_xor(mx.y, off));
      mx.z = fmaxf(mx.z, __shfl_xor(mx.z, off));
      mx.w = fmaxf(mx.w, __shfl_xor(mx.w, off));
    }
    __threadfence_block();
    float4 sm = make_float4(0.f, 0.f, 0.f, 0.f);
    for (int p = beg + lane; p < end; p += 64) {
      float4 lg = spill[p];
      float4 pv;
      pv.x = __expf(lg.x - mx.x);
      pv.y = __expf(lg.y - mx.y);
      pv.z = __expf(lg.z - mx.z);
      pv.w = __expf(lg.w - mx.w);
      spill[p] = pv;
      sm.x += pv.x;
      sm.y += pv.y;
      sm.z += pv.z;
      sm.w += pv.w;
    }
#pragma unroll
    for (int off = 32; off; off >>= 1) {
      sm.x += __shfl_xor(sm.x, off);
      sm.y += __shfl_xor(sm.y, off);
      sm.z += __shfl_xor(sm.z, off);
      sm.w += __shfl_xor(sm.w, off);
    }
    float4 inv;
    inv.x = 1.f / (sm.x + 1e-16f);
    inv.y = 1.f / (sm.y + 1e-16f);
    inv.z = 1.f / (sm.z + 1e-16f);
    inv.w = 1.f / (sm.w + 1e-16f);
    __threadfence_block();
    const float* af = (const float*)spill;
    for (int p = beg; p < end; ++p) {
      int s = csr_src[p];
      float av = af[(size_t)p * 4 + h] * ((h == 0) ? inv.x : (h == 1) ? inv.y : (h == 2) ? inv.z : inv.w);
      unsigned w = *(const unsigned*)(H16 + (size_t)s * 128 + lane * 2);
      acc0 = fmaf(av, bflo(w), acc0);
      acc1 = fmaf(av, bfhi(w), acc1);
    }
  }

  int c = lane * 2;
  unsigned skw = *(const unsigned*)(Sk16 + (size_t)n * 128 + c);
  float2 cbv = *(const float2*)(cb + c);
  float2 sbv = *(const float2*)(sb + c);
  float ox = fmaxf(acc0 + cbv.x + bflo(skw) + sbv.x, 0.f);
  float oy = fmaxf(acc1 + cbv.y + bfhi(skw) + sbv.y, 0.f);
  if (BF) {
    unsigned pk = (unsigned)f2bf(ox) | ((unsigned)f2bf(oy) << 16);
    *(unsigned*)(XnB + (size_t)n * 128 + c) = pk;
  }
  if (L2F) {
    float2 wv = *(const float2*)(c2w + c);
    float2 sv = *(const float2*)(s2w + c);
    float dh = ox * wv.x + oy * wv.y;
    float ds = ox * sv.x + oy * sv.y;
#pragma unroll
    for (int off = 32; off; off >>= 1) {
      dh += __shfl_xor(dh, off);
      ds += __shfl_xor(ds, off);
    }
    if (lane == 0) {
      h2[n] = dh;
      sk2[n] = ds;
      as2[n] = dh * c2as[0];
      ad2[n] = dh * c2ad[0];
    }
  }
}

// fused softmax + aggregate (H=1, C=1), wave-per-node
__global__ __launch_bounds__(TPB) void k_l2_smax_agg(const int* __restrict__ row_ptr, const int* __restrict__ csr_src,
                                                     const float* __restrict__ as2, const float* __restrict__ ad2,
                                                     const float* __restrict__ h2, const float* __restrict__ sk2,
                                                     const float* __restrict__ c2b, const float* __restrict__ s2b,
                                                     float* __restrict__ out, int N) {
  int n = blockIdx.x * 4 + (threadIdx.x >> 6);
  if (n >= N) return;
  int lane = threadIdx.x & 63;
  int beg = row_ptr[n], end = row_ptr[n + 1];
  int deg = end - beg;
  float ad = ad2[n];
  float num = 0.f, den = 0.f;

  if (deg <= 64) {
    float lg = -1e30f, hv = 0.f;
    if (lane < deg) {
      int s = csr_src[beg + lane];
      lg = lrelu(as2[s] + ad);
      hv = h2[s];
    }
    float mx = lg;
#pragma unroll
    for (int off = 32; off; off >>= 1) mx = fmaxf(mx, __shfl_xor(mx, off));
    float pv = (lane < deg) ? __expf(lg - mx) : 0.f;
    num = pv * hv;
    den = pv;
  } else {
    float mx = -1e30f;
    for (int p = beg + lane; p < end; p += 64) mx = fmaxf(mx, lrelu(as2[csr_src[p]] + ad));
#pragma unroll
    for (int off = 32; off; off >>= 1) mx = fmaxf(mx, __shfl_xor(mx, off));
    for (int p = beg + lane; p < end; p += 64) {
      int s = csr_src[p];
      float pv = __expf(lrelu(as2[s] + ad) - mx);
      num += pv * h2[s];
      den += pv;
    }
  }
#pragma unroll
  for (int off = 32; off; off >>= 1) {
    num += __shfl_xor(num, off);
    den += __shfl_xor(den, off);
  }
  if (lane == 0) {
    float v = num / (den + 1e-16f) + c2b[0] + sk2[n] + s2b[0];
    out[n] = 1.f / (1.f + __expf(-v));
  }
}

// ---------------- host orchestration -----------------------------------------
extern "C" void kernel_launch(void* const* d_in, const int* in_sizes, int n_in,
                              void* d_out, int out_size, void* d_ws, size_t ws_size,
                              hipStream_t stream) {
  const float* x = (const float*)d_in[0];
  const int* ei = (const int*)d_in[1];
  const float* c0_w = (const float*)d_in[3];
  const float* c0_as = (const float*)d_in[4];
  const float* c0_ad = (const float*)d_in[5];
  const float* c0_b = (const float*)d_in[6];
  const float* s0_w = (const float*)d_in[7];
  const float* s0_b = (const float*)d_in[8];
  const float* c1_w = (const float*)d_in[9];
  const float* c1_as = (const float*)d_in[10];
  const float* c1_ad = (const float*)d_in[11];
  const float* c1_b = (const float*)d_in[12];
  const float* s1_w = (const float*)d_in[13];
  const float* s1_b = (const float*)d_in[14];
  const float* c2_w = (const float*)d_in[15];
  const float* c2_as = (const float*)d_in[16];
  const float* c2_ad = (const float*)d_in[17];
  const float* c2_b = (const float*)d_in[18];
  const float* s2_w = (const float*)d_in[19];
  const float* s2_b = (const float*)d_in[20];

  const int N = in_sizes[0] / 128;
  const int E = in_sizes[1] / 2;
  const int EN = E + N;
  const int* srcE = ei;
  const int* dstE = ei + E;

  // bump allocator over d_ws
  char* wp_ = (char*)d_ws;
  auto alloc = [&](size_t bytes) -> void* {
    void* r = (void*)wp_;
    wp_ += (bytes + 255) & ~(size_t)255;
    return r;
  };
  unsigned short* Xb1 = (unsigned short*)alloc((size_t)N * 128 * 2);   // bf16 layer-1 input
  unsigned short* H16 = (unsigned short*)alloc((size_t)N * 128 * 2);   // bf16 lin out
  unsigned short* Sk16 = (unsigned short*)alloc((size_t)N * 128 * 2);  // bf16 skip
  float* a_s = (float*)alloc((size_t)N * 4 * 4);
  float* a_d = (float*)alloc((size_t)N * 4 * 4);
  float* spill = (float*)alloc((size_t)EN * 4 * 4);  // slow-path alpha spill
  unsigned short* Wb0 = (unsigned short*)alloc(256 * 128 * 2);
  unsigned short* Wb1 = (unsigned short*)alloc(256 * 128 * 2);
  int* deg = (int*)alloc((size_t)N * 4);
  int* row_ptr = (int*)alloc((size_t)(N + 1) * 4);
  int* cursor = (int*)alloc((size_t)N * 4);
  int* csum = (int*)alloc(4096 * 4);
  int* csr_src = (int*)alloc((size_t)EN * 4);
  float* h2 = (float*)alloc((size_t)N * 4);
  float* sk2 = (float*)alloc((size_t)N * 4);
  float* as2 = (float*)alloc((size_t)N * 4);
  float* ad2 = (float*)alloc((size_t)N * 4);

  const int gN4 = (N * 4 + TPB - 1) / TPB;
  const int nch = (N + TPB - 1) / TPB;
  const int gGemm = (N + 63) / 64;
  const int gWave = (N + 3) / 4;  // 4 waves/block, 1 node/wave

  // ---- CSR build (once per call; graph shared by all layers) ----
  hipMemsetAsync(deg, 0, (size_t)N * 4, stream);
  k_hist8<<<8 * RB, TPB, 0, stream>>>(dstE, E, N, deg);
  k_scan1<<<nch, TPB, 0, stream>>>(deg, N, csum);
  k_scan2<<<1, TPB, 0, stream>>>(csum, nch);
  k_scan3<<<nch, TPB, 0, stream>>>(deg, csum, N, EN, row_ptr, cursor);
  k_scatter8<<<8 * RB, TPB, 0, stream>>>(srcE, dstE, E, N, cursor, csr_src);

  // ---- shared prep ----
  k_prep_w2<<<512, 128, 0, stream>>>(c0_w, s0_w, c1_w, s1_w, Wb0, Wb1);

  // ---- layer 0 (fp32 input, fused convert) ----
  k_gemm_mfma<true><<<gGemm, TPB, 0, stream>>>(x, Wb0, H16, Sk16, N);
  k_asad<<<gN4, TPB, 0, stream>>>(H16, c0_as, c0_ad, a_s, a_d, N);
  k_smax_agg<true, false><<<gWave, TPB, 0, stream>>>(row_ptr, csr_src, (const float4*)a_s, (const float4*)a_d,
                                                     H16, Sk16, c0_b, s0_b, (float4*)spill, Xb1, nullptr, nullptr,
                                                     nullptr, nullptr, nullptr, nullptr, nullptr, nullptr, N);

  // ---- layer 1 (bf16 input; fused layer-2 linear in epilogue) ----
  k_gemm_mfma<false><<<gGemm, TPB, 0, stream>>>(Xb1, Wb1, H16, Sk16, N);
  k_asad<<<gN4, TPB, 0, stream>>>(H16, c1_as, c1_ad, a_s, a_d, N);
  k_smax_agg<false, true><<<gWave, TPB, 0, stream>>>(row_ptr, csr_src, (const float4*)a_s, (const float4*)a_d,
                                                     H16, Sk16, c1_b, s1_b, (float4*)spill, nullptr, c2_w, s2_w,
                                                     c2_as, c2_ad, h2, sk2, as2, ad2, N);

  // ---- layer 2 (H=1,C=1) ----
  k_l2_smax_agg<<<gWave, TPB, 0, stream>>>(row_ptr, csr_src, as2, ad2, h2, sk2, c2_b, s2_b, (float*)d_out, N);
}